// Round 1
// baseline (1030.463 us; speedup 1.0000x reference)
//
#include <hip/hip_runtime.h>

// ============================================================================
// CascadeRCNN: 3-stage cascade of {pyramid ROI-align -> fc1 -> fc2 -> heads}
// Design:
//  - Stages 0/1 need only the reg deltas (probs discarded) -> fc1/fc2 run in
//    SPLIT bf16 (hi+lo planes, 3 MFMA products) for ~fp32 accuracy, because
//    deltas feed the discontinuous pyramid-level select of the next stage.
//  - Stage 2 runs heads 0,1,2 batched (blockIdx.z) in plain bf16 (softmax is
//    smooth; error ~1e-4 < 3.8e-4 threshold).
//  - GEMM: m97 structure. 128x128x32 tile, 4 waves (2x2), 4x4 16x16x32 bf16
//    MFMA frags/wave, global_load_lds width=16 staging, split-K partials
//    (fp32) + epilogue reduce (bias/relu/bf16-hi-lo encode).
//  - Weights transposed+converted fp32->bf16(hi[,lo]) once per call in ws.
// ============================================================================

#define BM 128
#define BN 128
#define BK 32
#define K1 12544
#define MPAD 1024
#define NROI 1000

typedef __bf16 bf16_t;
typedef bf16_t bf16x8 __attribute__((ext_vector_type(8)));
typedef float f32x4 __attribute__((ext_vector_type(4)));

__device__ __forceinline__ unsigned short f2bf(float x) {
  unsigned u = __float_as_uint(x);
  return (unsigned short)((u + 0x7fffu + ((u >> 16) & 1u)) >> 16);
}
__device__ __forceinline__ float bf2f(unsigned short h) {
  return __uint_as_float(((unsigned)h) << 16);
}

__device__ __forceinline__ void gld_lds16(const void* g, void* l) {
  __builtin_amdgcn_global_load_lds(
      (__attribute__((address_space(1))) void*)g,
      (__attribute__((address_space(3))) void*)l, 16, 0, 0);
}

// ---------------------------------------------------------------------------
// GEMM: C_part[s][h][m][n] = A[h](M=1024 x K) * B[h]^T(Nh x K), bf16 MFMA.
// B is stored transposed (N-major, K contiguous). SPLIT adds lo-planes:
// acc += Ah*Bh + Ah*Bl + Al*Bh.
// grid: (Nh/128 * 8, S, H); block 256.
// ---------------------------------------------------------------------------
template <bool SPLIT>
__global__ __launch_bounds__(256, 2)
void gemm_bf16(const unsigned short* __restrict__ Ah,
               const unsigned short* __restrict__ Al,
               long long strideA_head,
               const unsigned short* __restrict__ Bh,
               const unsigned short* __restrict__ Bl,
               long long strideB_head,
               float* __restrict__ Cpart,
               int Nh, int K, int kcSteps)
{
  __shared__ __align__(16) unsigned short sAh[BM * BK];
  __shared__ __align__(16) unsigned short sBh[BN * BK];
  __shared__ __align__(16) unsigned short sAl[SPLIT ? BM * BK : 8];
  __shared__ __align__(16) unsigned short sBl[SPLIT ? BN * BK : 8];

  const int t = threadIdx.x;
  const int ntile = Nh / BN;
  const int bm = blockIdx.x / ntile;
  const int bn = blockIdx.x % ntile;
  const int s = blockIdx.y;
  const int h = blockIdx.z;
  const int H = gridDim.z;

  const unsigned short* Ab = Ah + (size_t)h * strideA_head + (size_t)bm * BM * K;
  const unsigned short* Bb = Bh + (size_t)h * strideB_head + (size_t)bn * BN * K;
  const unsigned short* Alb = SPLIT ? (Al + (size_t)h * strideA_head + (size_t)bm * BM * K) : (const unsigned short*)0;
  const unsigned short* Blb = SPLIT ? (Bl + (size_t)h * strideB_head + (size_t)bn * BN * K) : (const unsigned short*)0;

  int k0 = s * kcSteps * BK;
  int k1 = min(K, k0 + kcSteps * BK);

  const int srow = t >> 2;        // staging row within 64-row half
  const int skel = (t & 3) * 8;   // staging element offset within row
  const int lane = t & 63;
  const int wv = t >> 6;
  const int wm = (wv >> 1) * 64;
  const int wn = (wv & 1) * 64;
  const int lr = lane & 15;
  const int q = lane >> 4;

  f32x4 acc[4][4];
  const f32x4 z = {0.f, 0.f, 0.f, 0.f};
#pragma unroll
  for (int i = 0; i < 4; ++i)
#pragma unroll
    for (int j = 0; j < 4; ++j) acc[i][j] = z;

  for (int kk = k0; kk < k1; kk += BK) {
#pragma unroll
    for (int j = 0; j < 2; ++j) {
      int row = j * 64 + srow;
      gld_lds16(Ab + (size_t)row * K + kk + skel, (char*)sAh + j * 4096 + t * 16);
      gld_lds16(Bb + (size_t)row * K + kk + skel, (char*)sBh + j * 4096 + t * 16);
      if constexpr (SPLIT) {
        gld_lds16(Alb + (size_t)row * K + kk + skel, (char*)sAl + j * 4096 + t * 16);
        gld_lds16(Blb + (size_t)row * K + kk + skel, (char*)sBl + j * 4096 + t * 16);
      }
    }
    __syncthreads();

    bf16x8 af[4], bfr[4];
#pragma unroll
    for (int i = 0; i < 4; ++i) af[i] = *(const bf16x8*)&sAh[(wm + i * 16 + lr) * BK + q * 8];
#pragma unroll
    for (int j = 0; j < 4; ++j) bfr[j] = *(const bf16x8*)&sBh[(wn + j * 16 + lr) * BK + q * 8];
#pragma unroll
    for (int i = 0; i < 4; ++i)
#pragma unroll
      for (int j = 0; j < 4; ++j)
        acc[i][j] = __builtin_amdgcn_mfma_f32_16x16x32_bf16(af[i], bfr[j], acc[i][j], 0, 0, 0);

    if constexpr (SPLIT) {
      bf16x8 al[4], bl[4];
#pragma unroll
      for (int i = 0; i < 4; ++i) al[i] = *(const bf16x8*)&sAl[(wm + i * 16 + lr) * BK + q * 8];
#pragma unroll
      for (int j = 0; j < 4; ++j) bl[j] = *(const bf16x8*)&sBl[(wn + j * 16 + lr) * BK + q * 8];
#pragma unroll
      for (int i = 0; i < 4; ++i)
#pragma unroll
        for (int j = 0; j < 4; ++j) {
          acc[i][j] = __builtin_amdgcn_mfma_f32_16x16x32_bf16(af[i], bl[j], acc[i][j], 0, 0, 0);
          acc[i][j] = __builtin_amdgcn_mfma_f32_16x16x32_bf16(al[i], bfr[j], acc[i][j], 0, 0, 0);
        }
    }
    __syncthreads();
  }

  // write partials: layout ((s*H + h)*1024 + m)*Nh + n
  float* Cb = Cpart + ((size_t)(s * H + h) * MPAD + (size_t)bm * BM) * Nh + (size_t)bn * BN;
#pragma unroll
  for (int i = 0; i < 4; ++i)
#pragma unroll
    for (int j = 0; j < 4; ++j)
#pragma unroll
      for (int r = 0; r < 4; ++r) {
        int m = wm + i * 16 + q * 4 + r;   // C/D layout: row = quad*4+reg
        int n = wn + j * 16 + lr;          //             col = lane&15
        Cb[(size_t)m * Nh + n] = acc[i][j][r];
      }
}

// ---------------------------------------------------------------------------
// Epilogue: reduce S split-K partials + bias (+relu), emit bf16 hi[,lo][,f32]
// flags: 1=relu, 2=write hi, 4=write lo, 8=write f32
// ---------------------------------------------------------------------------
__global__ void epilogue_kernel(const float* __restrict__ Cpart, int S, int H, int Nh,
                                const float* __restrict__ bias, int nbias,
                                unsigned short* __restrict__ ohi,
                                unsigned short* __restrict__ olo,
                                float* __restrict__ of32, int flags)
{
  size_t idx = (size_t)blockIdx.x * 256 + threadIdx.x;
  size_t total = (size_t)H * MPAD * Nh;
  if (idx >= total) return;
  int n = (int)(idx % Nh);
  int h = (int)(idx / ((size_t)MPAD * Nh));
  float v = 0.f;
  for (int s = 0; s < S; ++s) v += Cpart[(size_t)s * total + idx];
  if (n < nbias) v += bias[(size_t)h * nbias + n];
  if (flags & 1) v = fmaxf(v, 0.f);
  if (flags & 8) of32[idx] = v;
  if (flags & 2) {
    unsigned short hi = f2bf(v);
    ohi[idx] = hi;
    if (flags & 4) olo[idx] = f2bf(v - bf2f(hi));
  }
}

// ---------------------------------------------------------------------------
// Transpose + fp32->bf16 hi/lo convert: W[H][K][N] -> T[H][N][K]
// lo written only for h < loHeads. grid (K/32, N/32, H), block 256.
// ---------------------------------------------------------------------------
__global__ void transpose_convert(const float* __restrict__ W,
                                  unsigned short* __restrict__ Thi,
                                  unsigned short* __restrict__ Tlo,
                                  int K, int N, int loHeads)
{
  __shared__ float tile[32][33];
  int kb = blockIdx.x * 32;
  int nb = blockIdx.y * 32;
  int h = blockIdx.z;
  const float* Wb = W + (size_t)h * K * N;
  int tc = threadIdx.x & 31;
  int tr = threadIdx.x >> 5;  // 0..7
#pragma unroll
  for (int j = 0; j < 4; ++j) {
    int kk = tr + j * 8;
    tile[kk][tc] = Wb[(size_t)(kb + kk) * N + nb + tc];
  }
  __syncthreads();
  size_t ob = (size_t)h * N * K;
  bool wlo = h < loHeads;
#pragma unroll
  for (int j = 0; j < 4; ++j) {
    int nn = tr + j * 8;
    float v = tile[tc][nn];
    unsigned short hi = f2bf(v);
    size_t o = ob + (size_t)(nb + nn) * K + kb + tc;
    Thi[o] = hi;
    if (wlo) Tlo[o] = f2bf(v - bf2f(hi));
  }
}

// cls_w (3,1024,81) -> w3t (3,128,1024) bf16, rows 81..127 zero. grid (128,3).
__global__ void transpose_cls(const float* __restrict__ W, unsigned short* __restrict__ T)
{
  int n = blockIdx.x, h = blockIdx.y, t = threadIdx.x;
  size_t ob = ((size_t)h * 128 + n) * 1024;
  if (n < 81) {
    for (int k = t; k < 1024; k += 256)
      T[ob + k] = f2bf(W[((size_t)h * 1024 + k) * 81 + n]);
  } else {
    for (int k = t; k < 1024; k += 256) T[ob + k] = 0;
  }
}

// ---------------------------------------------------------------------------
// Pyramid ROI-align, one block (256 thr = 256 channels) per roi.
// pooled layout [m][(py*7+px)*256 + c], bf16 hi (+lo).
// ---------------------------------------------------------------------------
__global__ void roi_align_kernel(const float* __restrict__ rois,
                                 const float* __restrict__ P2, const float* __restrict__ P3,
                                 const float* __restrict__ P4, const float* __restrict__ P5,
                                 unsigned short* __restrict__ phi,
                                 unsigned short* __restrict__ plo, int writeLo)
{
  int m = blockIdx.x;
  int c = threadIdx.x;
  const float* rp = rois + m * 4;
  float y1 = rp[0], x1 = rp[1], y2 = rp[2], x2 = rp[3];
  float hh = y2 - y1, ww = x2 - x1;
  float a = sqrtf(fmaxf(hh * ww, 1e-6f)) / 224.0f;
  float lvl = floorf(4.0f + log2f(a));
  lvl = fminf(fmaxf(lvl, 2.0f), 5.0f);
  int i = (int)lvl - 2;
  const float* f = (i == 0) ? P2 : (i == 1) ? P3 : (i == 2) ? P4 : P5;
  int H = 256 >> i;
  float stride = (float)(4 << i);
  float sy1 = y1 / stride, sx1 = x1 / stride;
  float dy = y2 / stride - sy1, dx = x2 / stride - sx1;
  size_t base = (size_t)m * K1 + c;
  for (int p = 0; p < 49; ++p) {
    int py = p / 7, px = p % 7;
    float ys = sy1 + ((py + 0.5f) / 7.0f) * dy;
    float xs = sx1 + ((px + 0.5f) / 7.0f) * dx;
    float y0f = fminf(fmaxf(floorf(ys), 0.0f), (float)(H - 1));
    float x0f = fminf(fmaxf(floorf(xs), 0.0f), (float)(H - 1));
    int y0 = (int)y0f, x0 = (int)x0f;
    int y1i = min(y0 + 1, H - 1), x1i = min(x0 + 1, H - 1);
    float wy = fminf(fmaxf(ys - y0f, 0.0f), 1.0f);
    float wx = fminf(fmaxf(xs - x0f, 0.0f), 1.0f);
    const float* r0 = f + (size_t)y0 * H * 256;
    const float* r1 = f + (size_t)y1i * H * 256;
    float v00 = r0[(size_t)x0 * 256 + c];
    float v01 = r0[(size_t)x1i * 256 + c];
    float v10 = r1[(size_t)x0 * 256 + c];
    float v11 = r1[(size_t)x1i * 256 + c];
    float v = v00 * (1.f - wy) * (1.f - wx) + v01 * (1.f - wy) * wx +
              v10 * wy * (1.f - wx) + v11 * wy * wx;
    unsigned short hi = f2bf(v);
    phi[base + p * 256] = hi;
    if (writeLo) plo[base + p * 256] = f2bf(v - bf2f(hi));
  }
}

// ---------------------------------------------------------------------------
// deltas = (hi+lo reconstructed h2) @ reg_w + reg_b, then delta2bbox.
// one block per roi, 256 threads.
// ---------------------------------------------------------------------------
__global__ void reg_delta_kernel(const unsigned short* __restrict__ h2h,
                                 const unsigned short* __restrict__ h2l,
                                 const float* __restrict__ rw, const float* __restrict__ rb,
                                 const float* __restrict__ rin, float* __restrict__ rout)
{
  int m = blockIdx.x, t = threadIdx.x;
  float s0 = 0, s1 = 0, s2 = 0, s3 = 0;
  const unsigned short* hr = h2h + (size_t)m * 1024;
  const unsigned short* lr = h2l + (size_t)m * 1024;
  for (int k = t; k < 1024; k += 256) {
    float hv = bf2f(hr[k]) + bf2f(lr[k]);
    const float* w = rw + (size_t)k * 4;
    s0 += hv * w[0]; s1 += hv * w[1]; s2 += hv * w[2]; s3 += hv * w[3];
  }
#pragma unroll
  for (int o = 32; o > 0; o >>= 1) {
    s0 += __shfl_xor(s0, o, 64);
    s1 += __shfl_xor(s1, o, 64);
    s2 += __shfl_xor(s2, o, 64);
    s3 += __shfl_xor(s3, o, 64);
  }
  __shared__ float part[4][4];
  int w = t >> 6;
  if ((t & 63) == 0) { part[w][0] = s0; part[w][1] = s1; part[w][2] = s2; part[w][3] = s3; }
  __syncthreads();
  if (t == 0) {
    float d0 = (part[0][0] + part[1][0] + part[2][0] + part[3][0] + rb[0]) * 0.1f;
    float d1 = (part[0][1] + part[1][1] + part[2][1] + part[3][1] + rb[1]) * 0.1f;
    float d2 = (part[0][2] + part[1][2] + part[2][2] + part[3][2] + rb[2]) * 0.2f;
    float d3 = (part[0][3] + part[1][3] + part[2][3] + part[3][3] + rb[3]) * 0.2f;
    const float* r = rin + m * 4;
    float y1 = r[0], x1 = r[1], y2 = r[2], x2 = r[3];
    float h = y2 - y1, wd = x2 - x1;
    float cy = y1 + 0.5f * h + d0 * h;
    float cx = x1 + 0.5f * wd + d1 * wd;
    float nh = h * expf(d2);
    float nw = wd * expf(d3);
    float* ro = rout + m * 4;
    ro[0] = fminf(fmaxf(cy - 0.5f * nh, 0.f), 1024.f);
    ro[1] = fminf(fmaxf(cx - 0.5f * nw, 0.f), 1024.f);
    ro[2] = fminf(fmaxf(cy + 0.5f * nh, 0.f), 1024.f);
    ro[3] = fminf(fmaxf(cx + 0.5f * nw, 0.f), 1024.f);
  }
}

// softmax over 81 logits per (roi, head), average 3 heads. block=128 per roi.
__global__ void softmax_avg_kernel(const float* __restrict__ logits, float* __restrict__ out)
{
  int m = blockIdx.x, t = threadIdx.x;
  __shared__ float sh[128];
  float pacc = 0.0f;
  for (int h = 0; h < 3; ++h) {
    float x = (t < 81) ? logits[((size_t)(h * MPAD + m)) * 128 + t] : -3.0e38f;
    sh[t] = x; __syncthreads();
    for (int o = 64; o > 0; o >>= 1) { if (t < o) sh[t] = fmaxf(sh[t], sh[t + o]); __syncthreads(); }
    float mx = sh[0]; __syncthreads();
    float e = (t < 81) ? expf(x - mx) : 0.0f;
    sh[t] = e; __syncthreads();
    for (int o = 64; o > 0; o >>= 1) { if (t < o) sh[t] += sh[t + o]; __syncthreads(); }
    float sum = sh[0]; __syncthreads();
    pacc += e / sum;
  }
  if (t < 81) out[(size_t)m * 81 + t] = pacc / 3.0f;
}

// ===========================================================================
extern "C" void kernel_launch(void* const* d_in, const int* in_sizes, int n_in,
                              void* d_out, int out_size, void* d_ws, size_t ws_size,
                              hipStream_t stream)
{
  const float* P2 = (const float*)d_in[0];
  const float* P3 = (const float*)d_in[1];
  const float* P4 = (const float*)d_in[2];
  const float* P5 = (const float*)d_in[3];
  const float* rois = (const float*)d_in[4];
  const float* fc1_w = (const float*)d_in[5];
  const float* fc1_b = (const float*)d_in[6];
  const float* fc2_w = (const float*)d_in[7];
  const float* fc2_b = (const float*)d_in[8];
  const float* cls_w = (const float*)d_in[9];
  const float* cls_b = (const float*)d_in[10];
  const float* reg_w = (const float*)d_in[11];
  const float* reg_b = (const float*)d_in[12];
  float* out = (float*)d_out;

  char* ws = (char*)d_ws;
  size_t off = 0;
  auto alloc = [&](size_t b) -> char* {
    char* p = ws + off;
    off = (off + b + 255) & ~(size_t)255;
    return p;
  };
  unsigned short* w1t_hi = (unsigned short*)alloc(3ull * 1024 * K1 * 2);
  unsigned short* w1t_lo = (unsigned short*)alloc(2ull * 1024 * K1 * 2);
  unsigned short* w2t_hi = (unsigned short*)alloc(3ull * 1024 * 1024 * 2);
  unsigned short* w2t_lo = (unsigned short*)alloc(2ull * 1024 * 1024 * 2);
  unsigned short* w3t    = (unsigned short*)alloc(3ull * 128 * 1024 * 2);
  unsigned short* phi    = (unsigned short*)alloc((size_t)MPAD * K1 * 2);
  unsigned short* plo    = (unsigned short*)alloc((size_t)MPAD * K1 * 2);
  unsigned short* h1_hi  = (unsigned short*)alloc(3ull * MPAD * 1024 * 2);
  unsigned short* h1_lo  = (unsigned short*)alloc((size_t)MPAD * 1024 * 2);
  unsigned short* h2_hi  = (unsigned short*)alloc(3ull * MPAD * 1024 * 2);
  unsigned short* h2_lo  = (unsigned short*)alloc((size_t)MPAD * 1024 * 2);
  float* logitsb         = (float*)alloc(3ull * MPAD * 128 * 4);
  float* r1              = (float*)alloc(16384);
  float* r2              = (float*)alloc(16384);
  float* cpart           = (float*)alloc(25165824);  // max split-K partials

  const long long hs1 = (long long)1024 * K1;     // w1t per-head stride
  const long long hs2 = (long long)1024 * 1024;   // w2t / h per-head stride

  dim3 b256(256);

  // --- weight conversion (per call; no cross-call caching allowed) ---
  hipLaunchKernelGGL(transpose_convert, dim3(K1 / 32, 32, 3), b256, 0, stream,
                     fc1_w, w1t_hi, w1t_lo, K1, 1024, 2);
  hipLaunchKernelGGL(transpose_convert, dim3(32, 32, 3), b256, 0, stream,
                     fc2_w, w2t_hi, w2t_lo, 1024, 1024, 2);
  hipLaunchKernelGGL(transpose_cls, dim3(128, 3), b256, 0, stream, cls_w, w3t);
  // zero pooled pad rows 1000..1023 (stay zero across stages)
  hipMemsetAsync(phi + (size_t)NROI * K1, 0, (size_t)(MPAD - NROI) * K1 * 2, stream);
  hipMemsetAsync(plo + (size_t)NROI * K1, 0, (size_t)(MPAD - NROI) * K1 * 2, stream);

  // --- stages 0,1: split-precision path, deltas only ---
  for (int st = 0; st < 2; ++st) {
    const float* rin = (st == 0) ? rois : r1;
    float* rout = (st == 0) ? r1 : r2;
    hipLaunchKernelGGL(roi_align_kernel, dim3(NROI), b256, 0, stream,
                       rin, P2, P3, P4, P5, phi, plo, 1);
    // fc1: M=1024,N=1024,K=12544, split bf16, split-K S=4 (392/4=98 steps)
    hipLaunchKernelGGL((gemm_bf16<true>), dim3(64, 4, 1), b256, 0, stream,
                       phi, plo, 0LL,
                       w1t_hi + (size_t)st * hs1, w1t_lo + (size_t)st * hs1, 0LL,
                       cpart, 1024, K1, 98);
    hipLaunchKernelGGL(epilogue_kernel, dim3(4096), b256, 0, stream,
                       cpart, 4, 1, 1024, fc1_b + st * 1024, 1024,
                       h1_hi, h1_lo, (float*)0, 1 | 2 | 4);
    // fc2: K=1024, S=4 (32/4=8 steps)
    hipLaunchKernelGGL((gemm_bf16<true>), dim3(64, 4, 1), b256, 0, stream,
                       h1_hi, h1_lo, 0LL,
                       w2t_hi + (size_t)st * hs2, w2t_lo + (size_t)st * hs2, 0LL,
                       cpart, 1024, 1024, 8);
    hipLaunchKernelGGL(epilogue_kernel, dim3(4096), b256, 0, stream,
                       cpart, 4, 1, 1024, fc2_b + st * 1024, 1024,
                       h2_hi, h2_lo, (float*)0, 1 | 2 | 4);
    hipLaunchKernelGGL(reg_delta_kernel, dim3(NROI), b256, 0, stream,
                       h2_hi, h2_lo, reg_w + (size_t)st * 1024 * 4, reg_b + st * 4,
                       rin, rout);
  }

  // --- stage 2: plain bf16, heads 0,1,2 batched via blockIdx.z ---
  hipLaunchKernelGGL(roi_align_kernel, dim3(NROI), b256, 0, stream,
                     r2, P2, P3, P4, P5, phi, plo, 0);
  hipLaunchKernelGGL((gemm_bf16<false>), dim3(64, 2, 3), b256, 0, stream,
                     phi, (const unsigned short*)0, 0LL,
                     w1t_hi, (const unsigned short*)0, hs1,
                     cpart, 1024, K1, 196);
  hipLaunchKernelGGL(epilogue_kernel, dim3(12288), b256, 0, stream,
                     cpart, 2, 3, 1024, fc1_b, 1024,
                     h1_hi, (unsigned short*)0, (float*)0, 1 | 2);
  hipLaunchKernelGGL((gemm_bf16<false>), dim3(64, 2, 3), b256, 0, stream,
                     h1_hi, (const unsigned short*)0, hs2,
                     w2t_hi, (const unsigned short*)0, hs2,
                     cpart, 1024, 1024, 16);
  hipLaunchKernelGGL(epilogue_kernel, dim3(12288), b256, 0, stream,
                     cpart, 2, 3, 1024, fc2_b, 1024,
                     h2_hi, (unsigned short*)0, (float*)0, 1 | 2);
  // cls: N=128 (81 real + zero pad), S=8 (32/8=4 steps)
  hipLaunchKernelGGL((gemm_bf16<false>), dim3(8, 8, 3), b256, 0, stream,
                     h2_hi, (const unsigned short*)0, hs2,
                     w3t, (const unsigned short*)0, (long long)128 * 1024,
                     cpart, 128, 1024, 4);
  hipLaunchKernelGGL(epilogue_kernel, dim3(1536), b256, 0, stream,
                     cpart, 8, 3, 128, cls_b, 81,
                     (unsigned short*)0, (unsigned short*)0, logitsb, 8);
  hipLaunchKernelGGL(softmax_avg_kernel, dim3(NROI), dim3(128), 0, stream,
                     logitsb, out);
}

// Round 2
// 894.672 us; speedup vs baseline: 1.1518x; 1.1518x over previous
//
#include <hip/hip_runtime.h>

// ============================================================================
// CascadeRCNN: 3-stage cascade of {pyramid ROI-align -> fc1 -> fc2 -> heads}
//  - Stages 0/1: SPLIT bf16 (hi+lo, 3 MFMA products) fc1/fc2 -> fp32-accurate
//    reg deltas (they feed the discontinuous pyramid-level select).
//  - Stage 2: plain bf16, heads 0,1,2 batched via blockIdx.z.
//  - GEMM: 128x128x32 tile, 4 waves, 16x16x32 bf16 MFMA, global_load_lds
//    width=16, split-K fp32 partials + epilogue reduce.
//  - R2: split-K widened for >=2-3 blocks/CU (was 1 -> occupancy 15%,
//    MfmaUtil 18%); XOR bank-swizzle on LDS col-group kills the 8-way
//    ds_read_b128 conflicts (9.6M cycles/dispatch). Stage-2 partials alias
//    w1t_lo (dead after stage 1) to keep peak ws at round-1 level.
// ============================================================================

#define BM 128
#define BN 128
#define BK 32
#define K1 12544
#define MPAD 1024
#define NROI 1000

typedef __bf16 bf16_t;
typedef bf16_t bf16x8 __attribute__((ext_vector_type(8)));
typedef float f32x4 __attribute__((ext_vector_type(4)));

__device__ __forceinline__ unsigned short f2bf(float x) {
  unsigned u = __float_as_uint(x);
  return (unsigned short)((u + 0x7fffu + ((u >> 16) & 1u)) >> 16);
}
__device__ __forceinline__ float bf2f(unsigned short h) {
  return __uint_as_float(((unsigned)h) << 16);
}

__device__ __forceinline__ void gld_lds16(const void* g, void* l) {
  __builtin_amdgcn_global_load_lds(
      (__attribute__((address_space(1))) void*)g,
      (__attribute__((address_space(3))) void*)l, 16, 0, 0);
}

// ---------------------------------------------------------------------------
// GEMM: C_part[s][h][m][n] = A[h](1024 x K) * B[h]^T(Nh x K), bf16 MFMA.
// LDS layout swizzled: global[row][grp] lives at LDS[row][grp ^ ((row>>1)&3)]
// (grp = 8-element / 16B column group). Makes frag ds_read_b128 ~conflict-free
// while keeping the global_load_lds wave-uniform-base+lane*16 dest.
// grid: (Mtiles*Ntiles, S, H); block 256.
// ---------------------------------------------------------------------------
template <bool SPLIT>
__global__ __launch_bounds__(256, 4)
void gemm_bf16(const unsigned short* __restrict__ Ah,
               const unsigned short* __restrict__ Al,
               long long strideA_head,
               const unsigned short* __restrict__ Bh,
               const unsigned short* __restrict__ Bl,
               long long strideB_head,
               float* __restrict__ Cpart,
               int Nh, int K, int kcSteps)
{
  __shared__ __align__(16) unsigned short sAh[BM * BK];
  __shared__ __align__(16) unsigned short sBh[BN * BK];
  __shared__ __align__(16) unsigned short sAl[SPLIT ? BM * BK : 8];
  __shared__ __align__(16) unsigned short sBl[SPLIT ? BN * BK : 8];

  const int t = threadIdx.x;
  const int ntile = Nh / BN;
  const int bm = blockIdx.x / ntile;
  const int bn = blockIdx.x % ntile;
  const int s = blockIdx.y;
  const int h = blockIdx.z;
  const int H = gridDim.z;

  const unsigned short* Ab = Ah + (size_t)h * strideA_head + (size_t)bm * BM * K;
  const unsigned short* Bb = Bh + (size_t)h * strideB_head + (size_t)bn * BN * K;
  const unsigned short* Alb = SPLIT ? (Al + (size_t)h * strideA_head + (size_t)bm * BM * K) : (const unsigned short*)0;
  const unsigned short* Blb = SPLIT ? (Bl + (size_t)h * strideB_head + (size_t)bn * BN * K) : (const unsigned short*)0;

  int k0 = s * kcSteps * BK;
  int k1 = min(K, k0 + kcSteps * BK);

  const int srow = t >> 2;                                  // staging row in 64-row half
  const int gsw = ((t & 3) ^ ((srow >> 1) & 3)) * 8;        // swizzled source col group
  const int lane = t & 63;
  const int wv = t >> 6;
  const int wm = (wv >> 1) * 64;
  const int wn = (wv & 1) * 64;
  const int lr = lane & 15;
  const int q = lane >> 4;
  const int sw = (lr >> 1) & 3;                             // frag-read swizzle
  const int cA = (q ^ sw) * 8;                              // swizzled frag col offset

  f32x4 acc[4][4];
  const f32x4 z = {0.f, 0.f, 0.f, 0.f};
#pragma unroll
  for (int i = 0; i < 4; ++i)
#pragma unroll
    for (int j = 0; j < 4; ++j) acc[i][j] = z;

  for (int kk = k0; kk < k1; kk += BK) {
#pragma unroll
    for (int j = 0; j < 2; ++j) {
      int row = j * 64 + srow;
      gld_lds16(Ab + (size_t)row * K + kk + gsw, (char*)sAh + j * 4096 + t * 16);
      gld_lds16(Bb + (size_t)row * K + kk + gsw, (char*)sBh + j * 4096 + t * 16);
      if constexpr (SPLIT) {
        gld_lds16(Alb + (size_t)row * K + kk + gsw, (char*)sAl + j * 4096 + t * 16);
        gld_lds16(Blb + (size_t)row * K + kk + gsw, (char*)sBl + j * 4096 + t * 16);
      }
    }
    __syncthreads();

    bf16x8 af[4], bfr[4];
#pragma unroll
    for (int i = 0; i < 4; ++i) af[i] = *(const bf16x8*)&sAh[(wm + i * 16 + lr) * BK + cA];
#pragma unroll
    for (int j = 0; j < 4; ++j) bfr[j] = *(const bf16x8*)&sBh[(wn + j * 16 + lr) * BK + cA];
#pragma unroll
    for (int i = 0; i < 4; ++i)
#pragma unroll
      for (int j = 0; j < 4; ++j)
        acc[i][j] = __builtin_amdgcn_mfma_f32_16x16x32_bf16(af[i], bfr[j], acc[i][j], 0, 0, 0);

    if constexpr (SPLIT) {
      bf16x8 al[4], bl[4];
#pragma unroll
      for (int i = 0; i < 4; ++i) al[i] = *(const bf16x8*)&sAl[(wm + i * 16 + lr) * BK + cA];
#pragma unroll
      for (int j = 0; j < 4; ++j) bl[j] = *(const bf16x8*)&sBl[(wn + j * 16 + lr) * BK + cA];
#pragma unroll
      for (int i = 0; i < 4; ++i)
#pragma unroll
        for (int j = 0; j < 4; ++j) {
          acc[i][j] = __builtin_amdgcn_mfma_f32_16x16x32_bf16(af[i], bl[j], acc[i][j], 0, 0, 0);
          acc[i][j] = __builtin_amdgcn_mfma_f32_16x16x32_bf16(al[i], bfr[j], acc[i][j], 0, 0, 0);
        }
    }
    __syncthreads();
  }

  // write partials: layout ((s*H + h)*1024 + m)*Nh + n
  float* Cb = Cpart + ((size_t)(s * H + h) * MPAD + (size_t)bm * BM) * Nh + (size_t)bn * BN;
#pragma unroll
  for (int i = 0; i < 4; ++i)
#pragma unroll
    for (int j = 0; j < 4; ++j)
#pragma unroll
      for (int r = 0; r < 4; ++r) {
        int m = wm + i * 16 + q * 4 + r;   // C/D layout: row = quad*4+reg
        int n = wn + j * 16 + lr;          //             col = lane&15
        Cb[(size_t)m * Nh + n] = acc[i][j][r];
      }
}

// ---------------------------------------------------------------------------
// Epilogue: reduce S split-K partials + bias (+relu), emit bf16 hi[,lo][,f32]
// flags: 1=relu, 2=write hi, 4=write lo, 8=write f32
// ---------------------------------------------------------------------------
__global__ void epilogue_kernel(const float* __restrict__ Cpart, int S, int H, int Nh,
                                const float* __restrict__ bias, int nbias,
                                unsigned short* __restrict__ ohi,
                                unsigned short* __restrict__ olo,
                                float* __restrict__ of32, int flags)
{
  size_t idx = (size_t)blockIdx.x * 256 + threadIdx.x;
  size_t total = (size_t)H * MPAD * Nh;
  if (idx >= total) return;
  int n = (int)(idx % Nh);
  int h = (int)(idx / ((size_t)MPAD * Nh));
  float v = 0.f;
  for (int s = 0; s < S; ++s) v += Cpart[(size_t)s * total + idx];
  if (n < nbias) v += bias[(size_t)h * nbias + n];
  if (flags & 1) v = fmaxf(v, 0.f);
  if (flags & 8) of32[idx] = v;
  if (flags & 2) {
    unsigned short hi = f2bf(v);
    ohi[idx] = hi;
    if (flags & 4) olo[idx] = f2bf(v - bf2f(hi));
  }
}

// ---------------------------------------------------------------------------
// Transpose + fp32->bf16 hi/lo convert: W[H][K][N] -> T[H][N][K]
// ---------------------------------------------------------------------------
__global__ void transpose_convert(const float* __restrict__ W,
                                  unsigned short* __restrict__ Thi,
                                  unsigned short* __restrict__ Tlo,
                                  int K, int N, int loHeads)
{
  __shared__ float tile[32][33];
  int kb = blockIdx.x * 32;
  int nb = blockIdx.y * 32;
  int h = blockIdx.z;
  const float* Wb = W + (size_t)h * K * N;
  int tc = threadIdx.x & 31;
  int tr = threadIdx.x >> 5;  // 0..7
#pragma unroll
  for (int j = 0; j < 4; ++j) {
    int kk = tr + j * 8;
    tile[kk][tc] = Wb[(size_t)(kb + kk) * N + nb + tc];
  }
  __syncthreads();
  size_t ob = (size_t)h * N * K;
  bool wlo = h < loHeads;
#pragma unroll
  for (int j = 0; j < 4; ++j) {
    int nn = tr + j * 8;
    float v = tile[tc][nn];
    unsigned short hi = f2bf(v);
    size_t o = ob + (size_t)(nb + nn) * K + kb + tc;
    Thi[o] = hi;
    if (wlo) Tlo[o] = f2bf(v - bf2f(hi));
  }
}

// cls_w (3,1024,81) -> w3t (3,128,1024) bf16, rows 81..127 zero. grid (128,3).
__global__ void transpose_cls(const float* __restrict__ W, unsigned short* __restrict__ T)
{
  int n = blockIdx.x, h = blockIdx.y, t = threadIdx.x;
  size_t ob = ((size_t)h * 128 + n) * 1024;
  if (n < 81) {
    for (int k = t; k < 1024; k += 256)
      T[ob + k] = f2bf(W[((size_t)h * 1024 + k) * 81 + n]);
  } else {
    for (int k = t; k < 1024; k += 256) T[ob + k] = 0;
  }
}

// ---------------------------------------------------------------------------
// Pyramid ROI-align, one block (256 thr = 256 channels) per roi.
// ---------------------------------------------------------------------------
__global__ void roi_align_kernel(const float* __restrict__ rois,
                                 const float* __restrict__ P2, const float* __restrict__ P3,
                                 const float* __restrict__ P4, const float* __restrict__ P5,
                                 unsigned short* __restrict__ phi,
                                 unsigned short* __restrict__ plo, int writeLo)
{
  int m = blockIdx.x;
  int c = threadIdx.x;
  const float* rp = rois + m * 4;
  float y1 = rp[0], x1 = rp[1], y2 = rp[2], x2 = rp[3];
  float hh = y2 - y1, ww = x2 - x1;
  float a = sqrtf(fmaxf(hh * ww, 1e-6f)) / 224.0f;
  float lvl = floorf(4.0f + log2f(a));
  lvl = fminf(fmaxf(lvl, 2.0f), 5.0f);
  int i = (int)lvl - 2;
  const float* f = (i == 0) ? P2 : (i == 1) ? P3 : (i == 2) ? P4 : P5;
  int H = 256 >> i;
  float stride = (float)(4 << i);
  float sy1 = y1 / stride, sx1 = x1 / stride;
  float dy = y2 / stride - sy1, dx = x2 / stride - sx1;
  size_t base = (size_t)m * K1 + c;
  for (int p = 0; p < 49; ++p) {
    int py = p / 7, px = p % 7;
    float ys = sy1 + ((py + 0.5f) / 7.0f) * dy;
    float xs = sx1 + ((px + 0.5f) / 7.0f) * dx;
    float y0f = fminf(fmaxf(floorf(ys), 0.0f), (float)(H - 1));
    float x0f = fminf(fmaxf(floorf(xs), 0.0f), (float)(H - 1));
    int y0 = (int)y0f, x0 = (int)x0f;
    int y1i = min(y0 + 1, H - 1), x1i = min(x0 + 1, H - 1);
    float wy = fminf(fmaxf(ys - y0f, 0.0f), 1.0f);
    float wx = fminf(fmaxf(xs - x0f, 0.0f), 1.0f);
    const float* r0 = f + (size_t)y0 * H * 256;
    const float* r1 = f + (size_t)y1i * H * 256;
    float v00 = r0[(size_t)x0 * 256 + c];
    float v01 = r0[(size_t)x1i * 256 + c];
    float v10 = r1[(size_t)x0 * 256 + c];
    float v11 = r1[(size_t)x1i * 256 + c];
    float v = v00 * (1.f - wy) * (1.f - wx) + v01 * (1.f - wy) * wx +
              v10 * wy * (1.f - wx) + v11 * wy * wx;
    unsigned short hi = f2bf(v);
    phi[base + p * 256] = hi;
    if (writeLo) plo[base + p * 256] = f2bf(v - bf2f(hi));
  }
}

// ---------------------------------------------------------------------------
// deltas = (hi+lo h2) @ reg_w + reg_b, then delta2bbox. one block per roi.
// ---------------------------------------------------------------------------
__global__ void reg_delta_kernel(const unsigned short* __restrict__ h2h,
                                 const unsigned short* __restrict__ h2l,
                                 const float* __restrict__ rw, const float* __restrict__ rb,
                                 const float* __restrict__ rin, float* __restrict__ rout)
{
  int m = blockIdx.x, t = threadIdx.x;
  float s0 = 0, s1 = 0, s2 = 0, s3 = 0;
  const unsigned short* hr = h2h + (size_t)m * 1024;
  const unsigned short* lr = h2l + (size_t)m * 1024;
  for (int k = t; k < 1024; k += 256) {
    float hv = bf2f(hr[k]) + bf2f(lr[k]);
    const float* w = rw + (size_t)k * 4;
    s0 += hv * w[0]; s1 += hv * w[1]; s2 += hv * w[2]; s3 += hv * w[3];
  }
#pragma unroll
  for (int o = 32; o > 0; o >>= 1) {
    s0 += __shfl_xor(s0, o, 64);
    s1 += __shfl_xor(s1, o, 64);
    s2 += __shfl_xor(s2, o, 64);
    s3 += __shfl_xor(s3, o, 64);
  }
  __shared__ float part[4][4];
  int w = t >> 6;
  if ((t & 63) == 0) { part[w][0] = s0; part[w][1] = s1; part[w][2] = s2; part[w][3] = s3; }
  __syncthreads();
  if (t == 0) {
    float d0 = (part[0][0] + part[1][0] + part[2][0] + part[3][0] + rb[0]) * 0.1f;
    float d1 = (part[0][1] + part[1][1] + part[2][1] + part[3][1] + rb[1]) * 0.1f;
    float d2 = (part[0][2] + part[1][2] + part[2][2] + part[3][2] + rb[2]) * 0.2f;
    float d3 = (part[0][3] + part[1][3] + part[2][3] + part[3][3] + rb[3]) * 0.2f;
    const float* r = rin + m * 4;
    float y1 = r[0], x1 = r[1], y2 = r[2], x2 = r[3];
    float h = y2 - y1, wd = x2 - x1;
    float cy = y1 + 0.5f * h + d0 * h;
    float cx = x1 + 0.5f * wd + d1 * wd;
    float nh = h * expf(d2);
    float nw = wd * expf(d3);
    float* ro = rout + m * 4;
    ro[0] = fminf(fmaxf(cy - 0.5f * nh, 0.f), 1024.f);
    ro[1] = fminf(fmaxf(cx - 0.5f * nw, 0.f), 1024.f);
    ro[2] = fminf(fmaxf(cy + 0.5f * nh, 0.f), 1024.f);
    ro[3] = fminf(fmaxf(cx + 0.5f * nw, 0.f), 1024.f);
  }
}

// softmax over 81 logits per (roi, head), average 3 heads. block=128 per roi.
__global__ void softmax_avg_kernel(const float* __restrict__ logits, float* __restrict__ out)
{
  int m = blockIdx.x, t = threadIdx.x;
  __shared__ float sh[128];
  float pacc = 0.0f;
  for (int h = 0; h < 3; ++h) {
    float x = (t < 81) ? logits[((size_t)(h * MPAD + m)) * 128 + t] : -3.0e38f;
    sh[t] = x; __syncthreads();
    for (int o = 64; o > 0; o >>= 1) { if (t < o) sh[t] = fmaxf(sh[t], sh[t + o]); __syncthreads(); }
    float mx = sh[0]; __syncthreads();
    float e = (t < 81) ? expf(x - mx) : 0.0f;
    sh[t] = e; __syncthreads();
    for (int o = 64; o > 0; o >>= 1) { if (t < o) sh[t] += sh[t + o]; __syncthreads(); }
    float sum = sh[0]; __syncthreads();
    pacc += e / sum;
  }
  if (t < 81) out[(size_t)m * 81 + t] = pacc / 3.0f;
}

// ===========================================================================
extern "C" void kernel_launch(void* const* d_in, const int* in_sizes, int n_in,
                              void* d_out, int out_size, void* d_ws, size_t ws_size,
                              hipStream_t stream)
{
  const float* P2 = (const float*)d_in[0];
  const float* P3 = (const float*)d_in[1];
  const float* P4 = (const float*)d_in[2];
  const float* P5 = (const float*)d_in[3];
  const float* rois = (const float*)d_in[4];
  const float* fc1_w = (const float*)d_in[5];
  const float* fc1_b = (const float*)d_in[6];
  const float* fc2_w = (const float*)d_in[7];
  const float* fc2_b = (const float*)d_in[8];
  const float* cls_w = (const float*)d_in[9];
  const float* cls_b = (const float*)d_in[10];
  const float* reg_w = (const float*)d_in[11];
  const float* reg_b = (const float*)d_in[12];
  float* out = (float*)d_out;

  char* ws = (char*)d_ws;
  size_t off = 0;
  auto alloc = [&](size_t b) -> char* {
    char* p = ws + off;
    off = (off + b + 255) & ~(size_t)255;
    return p;
  };
  unsigned short* w1t_hi = (unsigned short*)alloc(3ull * 1024 * K1 * 2);
  unsigned short* w1t_lo = (unsigned short*)alloc(2ull * 1024 * K1 * 2);  // dead after stage 1
  unsigned short* w2t_hi = (unsigned short*)alloc(3ull * 1024 * 1024 * 2);
  unsigned short* w2t_lo = (unsigned short*)alloc(2ull * 1024 * 1024 * 2);
  unsigned short* w3t    = (unsigned short*)alloc(3ull * 128 * 1024 * 2);
  unsigned short* phi    = (unsigned short*)alloc((size_t)MPAD * K1 * 2);
  unsigned short* plo    = (unsigned short*)alloc((size_t)MPAD * K1 * 2);
  unsigned short* h1_hi  = (unsigned short*)alloc(3ull * MPAD * 1024 * 2);
  unsigned short* h1_lo  = (unsigned short*)alloc((size_t)MPAD * 1024 * 2);
  unsigned short* h2_hi  = (unsigned short*)alloc(3ull * MPAD * 1024 * 2);
  unsigned short* h2_lo  = (unsigned short*)alloc((size_t)MPAD * 1024 * 2);
  float* logitsb         = (float*)alloc(3ull * MPAD * 128 * 4);
  float* r1              = (float*)alloc(16384);
  float* r2              = (float*)alloc(16384);

  // stage-0/1 split-K partials: whatever ws remains (S * 4 MiB needed)
  const size_t SLAB = (size_t)MPAD * 1024 * 4;  // 4 MiB per split-K slice
  size_t remain = (ws_size > off) ? (ws_size - off) : 0;
  int S01 = (int)(remain / SLAB);
  if (S01 > 8) S01 = 8;
  if (S01 < 1) S01 = 1;                          // round-1 layout guarantees >= 6
  float* cpart01 = (float*)(ws + off);
  // stage-2 partials alias w1t_lo (51.38 MB >= 4*3*4MiB = 50.33 MB needed)
  float* cpart2 = (float*)w1t_lo;

  const int fc1Steps01 = (392 + S01 - 1) / S01;
  const int fc2Steps01 = (32 + S01 - 1) / S01;

  const long long hs1 = (long long)1024 * K1;
  const long long hs2 = (long long)1024 * 1024;

  dim3 b256(256);

  // --- weight conversion (per call) ---
  hipLaunchKernelGGL(transpose_convert, dim3(K1 / 32, 32, 3), b256, 0, stream,
                     fc1_w, w1t_hi, w1t_lo, K1, 1024, 2);
  hipLaunchKernelGGL(transpose_convert, dim3(32, 32, 3), b256, 0, stream,
                     fc2_w, w2t_hi, w2t_lo, 1024, 1024, 2);
  hipLaunchKernelGGL(transpose_cls, dim3(128, 3), b256, 0, stream, cls_w, w3t);
  hipMemsetAsync(phi + (size_t)NROI * K1, 0, (size_t)(MPAD - NROI) * K1 * 2, stream);
  hipMemsetAsync(plo + (size_t)NROI * K1, 0, (size_t)(MPAD - NROI) * K1 * 2, stream);

  // --- stages 0,1: split-precision path, deltas only ---
  for (int st = 0; st < 2; ++st) {
    const float* rin = (st == 0) ? rois : r1;
    float* rout = (st == 0) ? r1 : r2;
    hipLaunchKernelGGL(roi_align_kernel, dim3(NROI), b256, 0, stream,
                       rin, P2, P3, P4, P5, phi, plo, 1);
    hipLaunchKernelGGL((gemm_bf16<true>), dim3(64, S01, 1), b256, 0, stream,
                       phi, plo, 0LL,
                       w1t_hi + (size_t)st * hs1, w1t_lo + (size_t)st * hs1, 0LL,
                       cpart01, 1024, K1, fc1Steps01);
    hipLaunchKernelGGL(epilogue_kernel, dim3(4096), b256, 0, stream,
                       cpart01, S01, 1, 1024, fc1_b + st * 1024, 1024,
                       h1_hi, h1_lo, (float*)0, 1 | 2 | 4);
    hipLaunchKernelGGL((gemm_bf16<true>), dim3(64, S01, 1), b256, 0, stream,
                       h1_hi, h1_lo, 0LL,
                       w2t_hi + (size_t)st * hs2, w2t_lo + (size_t)st * hs2, 0LL,
                       cpart01, 1024, 1024, fc2Steps01);
    hipLaunchKernelGGL(epilogue_kernel, dim3(4096), b256, 0, stream,
                       cpart01, S01, 1, 1024, fc2_b + st * 1024, 1024,
                       h2_hi, h2_lo, (float*)0, 1 | 2 | 4);
    hipLaunchKernelGGL(reg_delta_kernel, dim3(NROI), b256, 0, stream,
                       h2_hi, h2_lo, reg_w + (size_t)st * 1024 * 4, reg_b + st * 4,
                       rin, rout);
  }

  // --- stage 2: plain bf16, heads 0,1,2 batched via blockIdx.z ---
  hipLaunchKernelGGL(roi_align_kernel, dim3(NROI), b256, 0, stream,
                     r2, P2, P3, P4, P5, phi, plo, 0);
  // fc1: S=4 x 3 heads -> 768 blocks (3/CU), 98 steps each
  hipLaunchKernelGGL((gemm_bf16<false>), dim3(64, 4, 3), b256, 0, stream,
                     phi, (const unsigned short*)0, 0LL,
                     w1t_hi, (const unsigned short*)0, hs1,
                     cpart2, 1024, K1, 98);
  hipLaunchKernelGGL(epilogue_kernel, dim3(12288), b256, 0, stream,
                     cpart2, 4, 3, 1024, fc1_b, 1024,
                     h1_hi, (unsigned short*)0, (float*)0, 1 | 2);
  // fc2: S=4 x 3 heads -> 768 blocks, 8 steps each
  hipLaunchKernelGGL((gemm_bf16<false>), dim3(64, 4, 3), b256, 0, stream,
                     h1_hi, (const unsigned short*)0, hs2,
                     w2t_hi, (const unsigned short*)0, hs2,
                     cpart2, 1024, 1024, 8);
  hipLaunchKernelGGL(epilogue_kernel, dim3(12288), b256, 0, stream,
                     cpart2, 4, 3, 1024, fc2_b, 1024,
                     h2_hi, (unsigned short*)0, (float*)0, 1 | 2);
  // cls: N=128 (81 real + pad), S=8 -> 192 blocks, 4 steps
  hipLaunchKernelGGL((gemm_bf16<false>), dim3(8, 8, 3), b256, 0, stream,
                     h2_hi, (const unsigned short*)0, hs2,
                     w3t, (const unsigned short*)0, (long long)128 * 1024,
                     cpart2, 128, 1024, 4);
  hipLaunchKernelGGL(epilogue_kernel, dim3(1536), b256, 0, stream,
                     cpart2, 8, 3, 128, cls_b, 81,
                     (unsigned short*)0, (unsigned short*)0, logitsb, 8);
  hipLaunchKernelGGL(softmax_avg_kernel, dim3(NROI), dim3(128), 0, stream,
                     logitsb, out);
}